// Round 13
// baseline (93.805 us; speedup 1.0000x reference)
//
#include <hip/hip_runtime.h>

#define CS   224
#define HH   1024
#define WW   1024
#define HW   (HH * WW)
#define RT   16              // rows per column tile
#define NTIL (HH / RT)       // 64
#define NCOLG 2              // 1024 cols / (256 threads * 2 floats)
#define ROWS 8               // output rows per gather block (main path)
#define RGRP (CS / ROWS)     // 28

// ---- Pass 1: per-row inclusive cumsum into I -------------------------------
__global__ __launch_bounds__(256) void row_cumsum(
    const float* __restrict__ x, float* __restrict__ I)
{
    int row = blockIdx.x;                       // 0 .. 3*1024-1
    const float4* src = (const float4*)(x + (size_t)row * WW);
    float4*       dst = (float4*)(I + (size_t)row * WW);

    int t    = threadIdx.x;
    int lane = t & 63;
    int w    = t >> 6;

    float4 v = src[t];
    float s0 = v.x, s1 = s0 + v.y, s2 = s1 + v.z, s3 = s2 + v.w;
    float tsum = s3, sc = tsum;
    #pragma unroll
    for (int d = 1; d < 64; d <<= 1) {
        float o = __shfl_up(sc, d, 64);
        if (lane >= d) sc += o;
    }

    __shared__ float wsum[4];
    if (lane == 63) wsum[w] = sc;
    __syncthreads();
    float woff = 0.0f;
    #pragma unroll
    for (int k = 0; k < 4; ++k) woff += (k < w) ? wsum[k] : 0.0f;

    float ex = woff + sc - tsum;
    dst[t] = make_float4(ex + s0, ex + s1, ex + s2, ex + s3);
}

// ---- Pass 2: read-only tile column sums -> S -------------------------------
__global__ __launch_bounds__(256) void col_sum(
    const float* __restrict__ I, float* __restrict__ Sf)
{
    int b    = blockIdx.x;
    int tile = b % NTIL;
    int cg   = (b / NTIL) % NCOLG;
    int ch   = b / (NTIL * NCOLG);
    int c2   = cg * 256 + threadIdx.x;

    const float2* base = (const float2*)(I + (size_t)ch * HW
                                           + (size_t)(tile * RT) * WW) + c2;
    float2 acc = make_float2(0.0f, 0.0f);
    #pragma unroll
    for (int r = 0; r < RT; ++r) {
        float2 v = base[(size_t)r * (WW / 2)];
        acc.x += v.x; acc.y += v.y;
    }
    ((float2*)Sf)[(size_t)(ch * NTIL + tile) * (WW / 2) + c2] = acc;
}

// ---- Pass 3: inclusive scan of the 64 tile sums per column (wave/column) ---
__global__ __launch_bounds__(256) void scan_S(float* __restrict__ Sf)
{
    int gw   = (blockIdx.x * 256 + threadIdx.x) >> 6;   // global wave id
    int lane = threadIdx.x & 63;
    int c    = gw % WW;
    int ch   = gw / WW;

    size_t idx = ((size_t)(ch * NTIL + lane)) * WW + c;
    float v = Sf[idx];
    #pragma unroll
    for (int d = 1; d < 64; d <<= 1) {
        float o = __shfl_up(v, d, 64);
        if (lane >= d) v += o;
    }
    Sf[idx] = v;
}

// ---- Pass 4a (main): fused cumsum+offset, writing PAIR layout J ------------
// J[r][c] = (SAT[r][c], SAT[r][c+1]) as float2. Thread owns cols a=2*c2,a+1
// and redundantly accumulates col a+2 so the float4 store needs no neighbor.
__global__ __launch_bounds__(256) void col_apply_pair(
    const float* __restrict__ I, const float* __restrict__ Sf,
    float2* __restrict__ J)
{
    int b    = blockIdx.x;
    int tile = b % NTIL;
    int cg   = (b / NTIL) % NCOLG;
    int ch   = b / (NTIL * NCOLG);
    int c2   = cg * 256 + threadIdx.x;
    int a    = 2 * c2;                          // 0..1022
    int c    = (a + 2 <= WW - 1) ? a + 2 : WW - 1;

    float acc0 = 0.0f, acc1 = 0.0f, acc2 = 0.0f;
    if (tile > 0) {
        const float* Sr = Sf + (size_t)(ch * NTIL + tile - 1) * WW;
        float2 sv = *(const float2*)(Sr + a);
        acc0 = sv.x; acc1 = sv.y; acc2 = Sr[c];
    }

    const float* base = I + (size_t)ch * HW + (size_t)(tile * RT) * WW;
    float2*      Jb   = J + (size_t)ch * HW + (size_t)(tile * RT) * WW;

    #pragma unroll
    for (int r = 0; r < RT; ++r) {
        float2 v = *(const float2*)(base + (size_t)r * WW + a);
        float  u = base[(size_t)r * WW + c];
        acc0 += v.x; acc1 += v.y; acc2 += u;
        float4 st = make_float4(acc0, acc1, acc1, acc2);
        ((float4*)(Jb + (size_t)r * WW))[c2] = st;
    }
}

// ---- Pass 5a (main): gather from pair-SAT, 2 loads per output --------------
// Wave w handles output cols j in [56w, 56w+56); lanes 0..56 load the pair
// at A(j)=ox+lo(j)-1 (8B aligned); b-tap comes from lane j+1's pair via
// shfl_down + select on divisibility. Row math block-uniform (SALU).
__global__ __launch_bounds__(256) void cutouts_gather_pair(
    const float2* __restrict__ J,
    const int*   __restrict__ sizesv,
    const int*   __restrict__ oyv,
    const int*   __restrict__ oxv,
    float*       __restrict__ out)
{
    int b   = blockIdx.x;              // ((ch*128)+n)*28 + rg
    int rg  = b % RGRP;
    int rem = b / RGRP;
    int n   = rem % 128;
    int ch  = rem / 128;

    int tid = threadIdx.x;
    int w   = tid >> 6;
    int l   = tid & 63;

    int s   = sizesv[n];               // block-uniform -> scalar
    int oy_ = oyv[n];
    int ox_ = oxv[n];

    int j  = 56 * w + l;               // output col for l < 56
    int jl = (j <= CS) ? j : CS;       // load col index, clamp to 224
    int loj = (jl * s) / CS;
    int A   = ox_ + loj - 1;
    int Acl = (A < 0) ? 0 : A;

    int  hij = ((j + 1) * s + (CS - 1)) / CS;
    bool am  = (ox_ + loj) > 0;
    bool dv  = (((j + 1) * s) % CS) == 0;
    float rcpC = __builtin_amdgcn_rcpf((float)(hij - loj));

    const float2* Jc = J + (size_t)ch * HW;

    #pragma unroll
    for (int rr = 0; rr < ROWS; ++rr) {
        int i    = rg * ROWS + rr;
        int lo_i = (i * s) / CS;
        int nR   = ((i + 1) * s + (CS - 1)) / CS - lo_i;
        int r0   = oy_ + lo_i;
        int r1m  = r0 + nR - 1;
        bool rm  = (r0 > 0);
        int r0m  = rm ? (r0 - 1) : 0;

        float2 ph = Jc[(size_t)r1m * WW + Acl];
        float2 pl = Jc[(size_t)r0m * WW + Acl];

        float nhx = __shfl_down(ph.x, 1, 64);
        float nhy = __shfl_down(ph.y, 1, 64);
        float nlx = __shfl_down(pl.x, 1, 64);
        float nly = __shfl_down(pl.y, 1, 64);

        float hb = dv ? nhx : nhy;     // SAT[r1m][bcol]
        float lb = dv ? nlx : nly;     // SAT[r0m][bcol]

        float sum = (hb - (am ? ph.x : 0.0f))
                  - (rm ? (lb - (am ? pl.x : 0.0f)) : 0.0f);

        float rcpR = __builtin_amdgcn_rcpf((float)nR);
        if (l < 56)
            out[((size_t)((n * 3 + ch) * CS) + i) * CS + j] = sum * (rcpC * rcpR);
    }
}

// ---- Pass 4b/5b (fallback, ws < 24 MB): R11-proven path --------------------
__global__ __launch_bounds__(256) void col_apply(
    float* __restrict__ I, const float* __restrict__ Sf)
{
    int b    = blockIdx.x;
    int tile = b % NTIL;
    int cg   = (b / NTIL) % NCOLG;
    int ch   = b / (NTIL * NCOLG);
    int c2   = cg * 256 + threadIdx.x;

    float2 acc = make_float2(0.0f, 0.0f);
    if (tile > 0)
        acc = ((const float2*)Sf)[(size_t)(ch * NTIL + tile - 1) * (WW / 2) + c2];

    float2* base = (float2*)(I + (size_t)ch * HW + (size_t)(tile * RT) * WW) + c2;
    #pragma unroll
    for (int r = 0; r < RT; ++r) {
        float2 v = base[(size_t)r * (WW / 2)];
        acc.x += v.x; acc.y += v.y;
        base[(size_t)r * (WW / 2)] = acc;
    }
}

__global__ __launch_bounds__(256) void cutouts_gather_fb(
    const float* __restrict__ I,
    const int*   __restrict__ sizesv,
    const int*   __restrict__ oyv,
    const int*   __restrict__ oxv,
    float*       __restrict__ out)
{
    int b   = blockIdx.x;
    int rg  = b % 56;
    int rem = b / 56;
    int n   = rem % 128;
    int ch  = rem / 128;

    int j = threadIdx.x;
    if (j >= CS) return;

    int s   = sizesv[n];
    int oy_ = oyv[n];
    int ox_ = oxv[n];

    int lo_j = (j * s) / CS;
    int hi_j = ((j + 1) * s + (CS - 1)) / CS;
    int c0   = ox_ + lo_j;
    int bcol = ox_ + hi_j - 1;
    bool am  = (c0 > 0);
    int acol = am ? (c0 - 1) : 0;
    float rcpC = __builtin_amdgcn_rcpf((float)(hi_j - lo_j));

    const float* Ic = I + (size_t)ch * HW;

    #pragma unroll
    for (int rr = 0; rr < 4; ++rr) {
        int i    = rg * 4 + rr;
        int lo_i = (i * s) / CS;
        int nR   = ((i + 1) * s + (CS - 1)) / CS - lo_i;
        int r0   = oy_ + lo_i;
        int r1m  = r0 + nR - 1;
        bool rm  = (r0 > 0);
        int r0m  = rm ? (r0 - 1) : 0;

        const float* Rhi = Ic + (size_t)r1m * WW;
        const float* Rlo = Ic + (size_t)r0m * WW;

        float t11 = Rhi[bcol];
        float t10 = Rhi[acol];
        float t01 = Rlo[bcol];
        float t00 = Rlo[acol];

        float sum = t11 - (am ? t10 : 0.0f) - (rm ? t01 : 0.0f)
                  + ((am && rm) ? t00 : 0.0f);

        float rcpR = __builtin_amdgcn_rcpf((float)nR);
        out[((size_t)((n * 3 + ch) * CS) + i) * CS + j] = sum * (rcpC * rcpR);
    }
}

extern "C" void kernel_launch(void* const* d_in, const int* in_sizes, int n_in,
                              void* d_out, int out_size, void* d_ws, size_t ws_size,
                              hipStream_t stream) {
    const float* x     = (const float*)d_in[0];
    const int*   sizes = (const int*)d_in[1];
    const int*   oy    = (const int*)d_in[2];
    const int*   ox    = (const int*)d_in[3];
    float*       out   = (float*)d_out;

    const size_t J_BYTES = (size_t)3 * HW * sizeof(float2);   // 24 MB

    if (ws_size >= J_BYTES) {
        // Main path: J (pair SAT) in d_ws; I + S in the d_out tail
        // (gather reads only J and overwrites all of d_out afterwards).
        float2* J = (float2*)d_ws;
        float*  I = out + (out_size - 3 * HW);                 // 12 MB tail
        float*  S = I - 3 * NTIL * WW;                         // 768 KB below I

        row_cumsum<<<3 * HH, 256, 0, stream>>>(x, I);
        col_sum<<<3 * NCOLG * NTIL, 256, 0, stream>>>(I, S);
        scan_S<<<(3 * WW) / 4, 256, 0, stream>>>(S);
        col_apply_pair<<<3 * NCOLG * NTIL, 256, 0, stream>>>(I, S, J);
        cutouts_gather_pair<<<3 * 128 * RGRP, 256, 0, stream>>>(J, sizes, oy, ox, out);
    } else {
        // Fallback (proven R11 path): I in d_ws, S in d_out tail.
        float* I = (float*)d_ws;
        float* S = out + (out_size - 3 * NTIL * WW);

        row_cumsum<<<3 * HH, 256, 0, stream>>>(x, I);
        col_sum<<<3 * NCOLG * NTIL, 256, 0, stream>>>(I, S);
        scan_S<<<(3 * WW) / 4, 256, 0, stream>>>(S);
        col_apply<<<3 * NCOLG * NTIL, 256, 0, stream>>>(I, S);
        cutouts_gather_fb<<<3 * 128 * 56, 256, 0, stream>>>(I, sizes, oy, ox, out);
    }
}

// Round 15
// 66.597 us; speedup vs baseline: 1.4085x; 1.4085x over previous
//
#include <hip/hip_runtime.h>

#define CS   224
#define HH   1024
#define WW   1024
#define HW   (HH * WW)
#define RT   16              // rows per column tile
#define NTIL (HH / RT)       // 64
#define NCOLG 2              // 1024 cols / (256 threads * 2 floats)
#define ROWS 4               // output rows per gather block
#define S_FAST 449           // max s with ceil((223+s)/224) <= 3 (span fits dwordx4)

typedef float f4u __attribute__((ext_vector_type(4), aligned(4)));

// ---- Pass 1: per-row inclusive cumsum into I (3072 blocks) -----------------
__global__ __launch_bounds__(256) void row_cumsum(
    const float* __restrict__ x, float* __restrict__ I)
{
    int row = blockIdx.x;                       // 0 .. 3*1024-1
    const float4* src = (const float4*)(x + (size_t)row * WW);
    float4*       dst = (float4*)(I + (size_t)row * WW);

    int t    = threadIdx.x;
    int lane = t & 63;
    int w    = t >> 6;

    float4 v = src[t];
    float s0 = v.x, s1 = s0 + v.y, s2 = s1 + v.z, s3 = s2 + v.w;
    float tsum = s3, sc = tsum;
    #pragma unroll
    for (int d = 1; d < 64; d <<= 1) {
        float o = __shfl_up(sc, d, 64);
        if (lane >= d) sc += o;
    }

    __shared__ float wsum[4];
    if (lane == 63) wsum[w] = sc;
    __syncthreads();
    float woff = 0.0f;
    #pragma unroll
    for (int k = 0; k < 4; ++k) woff += (k < w) ? wsum[k] : 0.0f;

    float ex = woff + sc - tsum;
    dst[t] = make_float4(ex + s0, ex + s1, ex + s2, ex + s3);
}

// ---- Pass 2: read-only tile column sums -> S -------------------------------
__global__ __launch_bounds__(256) void col_sum(
    const float* __restrict__ I, float* __restrict__ Sf)
{
    int b    = blockIdx.x;
    int tile = b % NTIL;
    int cg   = (b / NTIL) % NCOLG;
    int ch   = b / (NTIL * NCOLG);
    int c2   = cg * 256 + threadIdx.x;

    const float2* base = (const float2*)(I + (size_t)ch * HW
                                           + (size_t)(tile * RT) * WW) + c2;
    float2 acc = make_float2(0.0f, 0.0f);
    #pragma unroll
    for (int r = 0; r < RT; ++r) {
        float2 v = base[(size_t)r * (WW / 2)];
        acc.x += v.x; acc.y += v.y;
    }
    ((float2*)Sf)[(size_t)(ch * NTIL + tile) * (WW / 2) + c2] = acc;
}

// ---- Pass 3: inclusive scan of the 64 tile sums per column (wave/column) ---
__global__ __launch_bounds__(256) void scan_S(float* __restrict__ Sf)
{
    int gw   = (blockIdx.x * 256 + threadIdx.x) >> 6;   // global wave id
    int lane = threadIdx.x & 63;
    int c    = gw % WW;
    int ch   = gw / WW;

    size_t idx = ((size_t)(ch * NTIL + lane)) * WW + c;
    float v = Sf[idx];
    #pragma unroll
    for (int d = 1; d < 64; d <<= 1) {
        float o = __shfl_up(v, d, 64);
        if (lane >= d) v += o;
    }
    Sf[idx] = v;
}

// ---- Pass 4: fused within-tile cumsum + scanned offset (one I pass) --------
__global__ __launch_bounds__(256) void col_apply(
    float* __restrict__ I, const float* __restrict__ Sf)
{
    int b    = blockIdx.x;
    int tile = b % NTIL;
    int cg   = (b / NTIL) % NCOLG;
    int ch   = b / (NTIL * NCOLG);
    int c2   = cg * 256 + threadIdx.x;

    float2 acc = make_float2(0.0f, 0.0f);
    if (tile > 0)
        acc = ((const float2*)Sf)[(size_t)(ch * NTIL + tile - 1) * (WW / 2) + c2];

    float2* base = (float2*)(I + (size_t)ch * HW + (size_t)(tile * RT) * WW) + c2;
    #pragma unroll
    for (int r = 0; r < RT; ++r) {
        float2 v = base[(size_t)r * (WW / 2)];
        acc.x += v.x; acc.y += v.y;
        base[(size_t)r * (WW / 2)] = acc;
    }
}

__device__ __forceinline__ float extract4(f4u q, int k) {
    float r = q.x;
    r = (k == 1) ? q.y : r;
    r = (k == 2) ? q.z : r;
    r = (k == 3) ? q.w : r;
    return r;
}

// ---- Pass 5: gather. Block = 4 output rows of one (n,ch); lane = column. ---
// s <= 449 (block-uniform): span bcol-acol = nC <= ceil((223+449)/224) = 3,
// so ONE 4B-aligned dwordx4 per SAT row captures both taps -> 2 loads/output.
// Otherwise the proven 4x scalar-tap path.
__global__ __launch_bounds__(256) void cutouts_gather(
    const float* __restrict__ I,
    const int*   __restrict__ sizesv,
    const int*   __restrict__ oyv,
    const int*   __restrict__ oxv,
    float*       __restrict__ out)
{
    int b   = blockIdx.x;              // ((ch*128)+n)*56 + rg
    int rg  = b % (CS / ROWS);
    int rem = b / (CS / ROWS);
    int n   = rem % 128;
    int ch  = rem / 128;               // slowest: working set = one 4MB plane

    int j = threadIdx.x;
    if (j >= CS) return;

    int s   = sizesv[n];               // block-uniform -> scalar
    int oy_ = oyv[n];
    int ox_ = oxv[n];

    // per-lane column math, once for all ROWS rows
    int lo_j = (j * s) / CS;
    int hi_j = ((j + 1) * s + (CS - 1)) / CS;
    int c0   = ox_ + lo_j;
    int bcol = ox_ + hi_j - 1;                  // >= 0 always
    bool am  = (c0 > 0);
    int acol = am ? (c0 - 1) : 0;
    float rcpC = __builtin_amdgcn_rcpf((float)(hi_j - lo_j));

    const float* Ic = I + (size_t)ch * HW;

    // row-level values (block-uniform -> SALU)
    int  r1mv[ROWS], r0mv[ROWS];
    bool rmv[ROWS];
    float rcpA[ROWS];
    #pragma unroll
    for (int rr = 0; rr < ROWS; ++rr) {
        int i    = rg * ROWS + rr;
        int lo_i = (i * s) / CS;
        int nR   = ((i + 1) * s + (CS - 1)) / CS - lo_i;
        int r0   = oy_ + lo_i;
        r1mv[rr] = r0 + nR - 1;
        rmv[rr]  = (r0 > 0);
        r0mv[rr] = rmv[rr] ? (r0 - 1) : 0;
        rcpA[rr] = rcpC * __builtin_amdgcn_rcpf((float)nR);
    }

    if (s <= S_FAST) {
        // fast path: one dwordx4 per SAT row holds both taps (span <= 3)
        int basec = acol < (WW - 4) ? acol : (WW - 4);
        int oa = acol - basec;                   // 0..3
        int ob = bcol - basec;                   // 0..3

        f4u qh[ROWS], ql[ROWS];
        #pragma unroll
        for (int rr = 0; rr < ROWS; ++rr) {
            qh[rr] = *(const f4u*)(Ic + (size_t)r1mv[rr] * WW + basec);
            ql[rr] = *(const f4u*)(Ic + (size_t)r0mv[rr] * WW + basec);
        }
        #pragma unroll
        for (int rr = 0; rr < ROWS; ++rr) {
            int i = rg * ROWS + rr;
            float t11 = extract4(qh[rr], ob);
            float t10 = extract4(qh[rr], oa);
            float t01 = extract4(ql[rr], ob);
            float t00 = extract4(ql[rr], oa);
            float sum = (t11 - (am ? t10 : 0.0f))
                      - (rmv[rr] ? (t01 - (am ? t00 : 0.0f)) : 0.0f);
            out[((size_t)((n * 3 + ch) * CS) + i) * CS + j] = sum * rcpA[rr];
        }
    } else {
        // large-s path: 4 independent scalar taps (proven R11)
        float vhb[ROWS], vha[ROWS], vlb[ROWS], vla[ROWS];
        #pragma unroll
        for (int rr = 0; rr < ROWS; ++rr) {
            const float* Rhi = Ic + (size_t)r1mv[rr] * WW;
            const float* Rlo = Ic + (size_t)r0mv[rr] * WW;
            vhb[rr] = Rhi[bcol];
            vha[rr] = Rhi[acol];
            vlb[rr] = Rlo[bcol];
            vla[rr] = Rlo[acol];
        }
        #pragma unroll
        for (int rr = 0; rr < ROWS; ++rr) {
            int i = rg * ROWS + rr;
            float sum = vhb[rr]
                      - (am ? vha[rr] : 0.0f)
                      - (rmv[rr] ? vlb[rr] : 0.0f)
                      + ((am && rmv[rr]) ? vla[rr] : 0.0f);
            out[((size_t)((n * 3 + ch) * CS) + i) * CS + j] = sum * rcpA[rr];
        }
    }
}

extern "C" void kernel_launch(void* const* d_in, const int* in_sizes, int n_in,
                              void* d_out, int out_size, void* d_ws, size_t ws_size,
                              hipStream_t stream) {
    const float* x     = (const float*)d_in[0];
    const int*   sizes = (const int*)d_in[1];
    const int*   oy    = (const int*)d_in[2];
    const int*   ox    = (const int*)d_in[3];
    float*       out   = (float*)d_out;
    float*       I     = (float*)d_ws;               // 12 MB

    // Tile sums S (3*64*1024 floats = 768 KB) in the tail of d_out;
    // fully consumed by col_apply before the gather overwrites all of d_out.
    float* S = out + (out_size - 3 * NTIL * WW);

    row_cumsum<<<3 * HH, 256, 0, stream>>>(x, I);
    col_sum<<<3 * NCOLG * NTIL, 256, 0, stream>>>(I, S);
    scan_S<<<(3 * WW) / 4, 256, 0, stream>>>(S);       // 768 blocks
    col_apply<<<3 * NCOLG * NTIL, 256, 0, stream>>>(I, S);

    int blocks = 3 * 128 * (CS / ROWS);               // 21504
    cutouts_gather<<<blocks, 256, 0, stream>>>(I, sizes, oy, ox, out);
}